// Round 7
// baseline (11721.572 us; speedup 1.0000x reference)
//
#include <hip/hip_runtime.h>
#include <math.h>

#define BB   256   // batch
#define HH   512   // hidden
#define NWG  256
#define NTHR 1024
#define TT   64    // steps
#define NOUT 33
#define CD   128   // cond dim
#define SZ   (HH*BB)
#define LOFF (4*HH*HH)   // layer stride in Wih/Whh
#define BOFF (4*HH)      // layer stride in bih/bhh
#define WBLK (16*1024)   // floats per WG in wsT: [1024 k][16 slots]

__device__ __forceinline__ float sigm(float x)  { return 1.0f/(1.0f+expf(-x)); }
__device__ __forceinline__ float lrelu(float x) { return x >= 0.0f ? x : 0.01f*x; }

// Monotonic 2-level grid barrier: 8 group counters (32 arrivals) -> 1 global (8) -> gen.
__device__ __forceinline__ void gbar(unsigned* bar, unsigned ep, int grp) {
  __syncthreads();
  if (threadIdx.x == 0) {
    __builtin_amdgcn_fence(__ATOMIC_RELEASE, "agent");
    unsigned old = __hip_atomic_fetch_add(&bar[grp*16], 1u, __ATOMIC_RELAXED, __HIP_MEMORY_SCOPE_AGENT);
    if (old == ep*32u + 31u) {
      unsigned o2 = __hip_atomic_fetch_add(&bar[128], 1u, __ATOMIC_RELAXED, __HIP_MEMORY_SCOPE_AGENT);
      if (o2 == ep*8u + 7u)
        __hip_atomic_store(&bar[144], ep+1u, __ATOMIC_RELAXED, __HIP_MEMORY_SCOPE_AGENT);
    }
    while (__hip_atomic_load(&bar[144], __ATOMIC_RELAXED, __HIP_MEMORY_SCOPE_AGENT) < ep+1u)
      __builtin_amdgcn_s_sleep(8);
    __builtin_amdgcn_fence(__ATOMIC_ACQUIRE, "agent");
  }
  __syncthreads();
}

// Pre-kernel: transpose this WG's 16 gate-row weight streams into [k][16] blocks
// so the decoder can read 64B-contiguous wave-uniform chunks via the scalar pipe.
extern "C" __global__ void __launch_bounds__(256)
transpose_weights(const float* __restrict__ Wih, const float* __restrict__ Whh,
                  float* __restrict__ wsT)
{
  const int w   = blockIdx.x;
  const int tid = threadIdx.x;
  float* dst = wsT + w*WBLK;
  #pragma unroll 1
  for (int j = 0; j < 64; ++j) {
    int i  = j*256 + tid;        // i = ri*1024 + k
    int ri = i >> 10, k = i & 1023;
    int l  = k >> 9,  kk = k & 511;
    int r2 = ri & 7,  u = r2 >> 2, g = r2 & 3;
    const float* src = (ri < 8) ? Wih : Whh;
    dst[k*16 + ri] = src[l*LOFF + (g*HH + 2*w + u)*HH + kk];
  }
}

// One pass: 64 k, 8 gate rows, one batch col/lane. Weights via wave-uniform
// scalar loads (never-written __restrict__ -> s_load), activations per-lane.
__device__ __forceinline__ void lstm_pass(const float* __restrict__ wbase,
    const float* __restrict__ xp, const float* __restrict__ hp,
    float* __restrict__ redp)
{
  float acc[8];
  #pragma unroll
  for (int r = 0; r < 8; ++r) acc[r] = 0.0f;
  float qx[4], qh[4], px[4], ph[4];
  #pragma unroll
  for (int j = 0; j < 4; ++j) { qx[j] = xp[j*BB]; qh[j] = hp[j*BB]; }
  #pragma unroll 1
  for (int blk = 0; blk < 16; ++blk) {
    if (blk+1 < 16) {
      #pragma unroll
      for (int j = 0; j < 4; ++j) {
        px[j] = xp[(blk*4+4+j)*BB];
        ph[j] = hp[(blk*4+4+j)*BB];
      }
    }
    #pragma unroll
    for (int j = 0; j < 4; ++j) {
      const float* wk = wbase + (blk*4+j)*16;
      float4 wi0 = *(const float4*)(wk+0);
      float4 wi1 = *(const float4*)(wk+4);
      float4 wh0 = *(const float4*)(wk+8);
      float4 wh1 = *(const float4*)(wk+12);
      float x = qx[j], h = qh[j];
      acc[0] += wi0.x*x + wh0.x*h;
      acc[1] += wi0.y*x + wh0.y*h;
      acc[2] += wi0.z*x + wh0.z*h;
      acc[3] += wi0.w*x + wh0.w*h;
      acc[4] += wi1.x*x + wh1.x*h;
      acc[5] += wi1.y*x + wh1.y*h;
      acc[6] += wi1.z*x + wh1.z*h;
      acc[7] += wi1.w*x + wh1.w*h;
    }
    #pragma unroll
    for (int j = 0; j < 4; ++j) { qx[j] = px[j]; qh[j] = ph[j]; }
  }
  #pragma unroll
  for (int r = 0; r < 8; ++r) redp[r*BB] = acc[r];
}

// One LSTM layer phase. Wave = (bg, ks); two passes; partials -> red[64][BB].
__device__ __forceinline__ void lstm_phase(const float* __restrict__ wT,
    const float* __restrict__ bias, float* __restrict__ red,
    const float* __restrict__ xsrc, const float* __restrict__ hsrc,
    float* __restrict__ hdst, float* __restrict__ cbuf,
    int hu0, int tid, int ks, int bg)
{
  const int lane  = tid & 63;
  const int kbase = ks*64;
  const float* wbase = wT + kbase*16;
  #pragma unroll 1
  for (int p = 0; p < 2; ++p) {
    const int b = bg*128 + p*64 + lane;
    lstm_pass(wbase, xsrc + kbase*BB + b, hsrc + kbase*BB + b, red + (ks*8)*BB + b);
  }
  __syncthreads();
  if (tid < 512) {
    const int b = tid & 255, u = tid >> 8;
    float g[4];
    #pragma unroll
    for (int gg = 0; gg < 4; ++gg) {
      float s = bias[u*4+gg];
      #pragma unroll
      for (int k2 = 0; k2 < 8; ++k2) s += red[(k2*8 + u*4+gg)*BB + b];
      g[gg] = s;
    }
    const int hu = hu0 + u;
    float ig = sigm(g[0]), fg = sigm(g[1]);
    float gv = tanhf(g[2]), og = sigm(g[3]);
    float cn = fg*cbuf[hu*BB+b] + ig*gv;
    cbuf[hu*BB+b] = cn;
    hdst[hu*BB+b] = og*tanhf(cn);
  }
}

extern "C" __global__ void __launch_bounds__(NTHR)
decoder_kernel(const float* __restrict__ h0, const float* __restrict__ c0,
               const float* __restrict__ conds, const float* __restrict__ emb,
               const float* __restrict__ wsT, const float* __restrict__ bih,
               const float* __restrict__ bhh, const float* __restrict__ fcW,
               const float* __restrict__ fcb, const float* __restrict__ fc2W,
               const float* __restrict__ fc2b, const float* __restrict__ fc3W,
               const float* __restrict__ fc3b,
               float* __restrict__ out, unsigned* bar, float* wsf)
{
  const int w   = blockIdx.x;
  const int tid = threadIdx.x;
  const int hu0 = 2*w;
  const int grp = w & 7;
  const int wv  = tid >> 6;        // wave 0..15
  const int bg  = wv & 1;          // batch half
  const int ks  = wv >> 1;         // k-slice 0..7

  float* xbuf  = wsf;
  float* h1b0  = wsf + 1*SZ;
  float* h1b1  = wsf + 2*SZ;
  float* h2b0  = wsf + 3*SZ;
  float* h2b1  = wsf + 4*SZ;
  float* c1b   = wsf + 5*SZ;
  float* c2b   = wsf + 6*SZ;
  float* condb = wsf + 7*SZ;
  float* yb    = wsf + 8*SZ;
  float* condY = wsf + 9*SZ;

  const float* wT1 = wsT + w*WBLK;            // layer 0: k 0..511
  const float* wT2 = wsT + w*WBLK + 512*16;   // layer 1: k 512..1023

  __shared__ float red[64*BB];     // 64KB reduction scratch
  __shared__ float bias1[8], bias2[8], biasc[2];
  __shared__ float lds_y[HH];
  __shared__ float part[NOUT][17];
  __shared__ int   lds_act;
  __shared__ float lds_pad[3072];  // push LDS > 80KB -> exactly 1 WG/CU
  if (tid == 0) ((volatile float*)lds_pad)[0] = 0.0f;

  // ---- init ----
  if (tid < 512) {
    const int b = tid & 255, u = tid >> 8;
    const int k = hu0 + u;
    xbuf[k*BB+b] = (k < HH-1) ? emb[k] : 0.0f;   // emb[SOS=0][k], dur=0
    h1b0[k*BB+b] = h0[b*HH + k];
    c1b [k*BB+b] = c0[b*HH + k];
    h2b0[k*BB+b] = h0[(BB+b)*HH + k];
    c2b [k*BB+b] = c0[(BB+b)*HH + k];
    float a = fcb[k];
    const float4* cp = (const float4*)(conds + b*CD);
    const float4* wp = (const float4*)(fcW + k*CD);   // k wave-uniform -> scalar
    #pragma unroll 8
    for (int q = 0; q < CD/4; ++q) {
      float4 c4 = cp[q], w4 = wp[q];
      a += c4.x*w4.x + c4.y*w4.y + c4.z*w4.z + c4.w*w4.w;
    }
    condb[k*BB+b] = lrelu(a);
  }
  if (tid < 8) {
    int u = tid >> 2, g = tid & 3;
    bias1[tid] = bih[g*HH + hu0 + u] + bhh[g*HH + hu0 + u];
    bias2[tid] = bih[BOFF + g*HH + hu0 + u] + bhh[BOFF + g*HH + hu0 + u];
  }
  if (tid < 2) biasc[tid] = fc2b[hu0 + tid];

  unsigned ep = 0;
  gbar(bar, ep++, grp);

  // condY[hu][b]: cond-branch through fc2 (step-invariant)
  if (tid < 512) {
    const int b = tid & 255, u = tid >> 8;
    const float* wr = fc2W + (hu0+u)*HH;   // wave-uniform row -> scalar stream
    float s = 0.0f;
    #pragma unroll 4
    for (int k = 0; k < HH; k += 4) {
      float4 w4 = *(const float4*)(wr + k);
      s += w4.x*condb[k*BB+b]     + w4.y*condb[(k+1)*BB+b]
         + w4.z*condb[(k+2)*BB+b] + w4.w*condb[(k+3)*BB+b];
    }
    condY[(hu0+u)*BB + b] = s;
  }
  __syncthreads();

  for (int t = 0; t < TT; ++t) {
    const bool par = (t & 1) != 0;
    float* h1r = par ? h1b1 : h1b0;
    float* h1w = par ? h1b0 : h1b1;
    float* h2r = par ? h2b1 : h2b0;
    float* h2w = par ? h2b0 : h2b1;

    // Phase A: layer 0
    lstm_phase(wT1, bias1, red, xbuf, h1r, h1w, c1b, hu0, tid, ks, bg);
    gbar(bar, ep++, grp);
    // Phase B: layer 1
    lstm_phase(wT2, bias2, red, h1w, h2r, h2w, c2b, hu0, tid, ks, bg);
    gbar(bar, ep++, grp);
    // Phase C: y = leaky(h2 @ fc2W^T + fc2b + condY), rows hu0..hu0+1
    {
      const int b = tid & 255, s4 = tid >> 8;   // s4: k-slice of 128
      float a0 = 0.0f, a1 = 0.0f;
      const float* hp = h2w + (s4*128)*BB + b;
      const float* w0 = fc2W + (hu0+0)*HH + s4*128;  // wave-uniform scalar streams
      const float* w1 = fc2W + (hu0+1)*HH + s4*128;
      float q[4], p[4];
      #pragma unroll
      for (int j = 0; j < 4; ++j) q[j] = hp[j*BB];
      #pragma unroll 1
      for (int blk = 0; blk < 32; ++blk) {
        if (blk+1 < 32) {
          #pragma unroll
          for (int j = 0; j < 4; ++j) p[j] = hp[(blk*4+4+j)*BB];
        }
        float4 wa = *(const float4*)(w0 + blk*4);
        float4 wb = *(const float4*)(w1 + blk*4);
        a0 += wa.x*q[0] + wa.y*q[1] + wa.z*q[2] + wa.w*q[3];
        a1 += wb.x*q[0] + wb.y*q[1] + wb.z*q[2] + wb.w*q[3];
        #pragma unroll
        for (int j = 0; j < 4; ++j) q[j] = p[j];
      }
      red[(s4*2+0)*BB + b] = a0;
      red[(s4*2+1)*BB + b] = a1;
    }
    __syncthreads();
    if (tid < 512) {
      const int b = tid & 255, u = tid >> 8;
      float s = biasc[u] + condY[(hu0+u)*BB + b];
      #pragma unroll
      for (int s4 = 0; s4 < 4; ++s4) s += red[(s4*2+u)*BB + b];
      yb[(hu0+u)*BB + b] = lrelu(s);
    }
    gbar(bar, ep++, grp);
    // Phase D: WG w handles batch row w: fc3, argmax, next x
    {
      if (tid < 512) lds_y[tid] = yb[tid*BB + w];
      __syncthreads();
      int o = 0, kc = 0;
      bool active = false;
      if (tid < 512)        { o = tid & 31; kc = tid >> 5; active = true; }
      else if (tid < 528)   { o = 32;       kc = tid - 512; active = true; }
      if (active) {
        float p = 0.0f;
        const float* fw = fc3W + o*HH + kc*32;
        #pragma unroll
        for (int k2 = 0; k2 < 32; ++k2) p += fw[k2] * lds_y[kc*32 + k2];
        part[o][kc] = p;
      }
      __syncthreads();
      float predv = -1e30f;
      if (tid < NOUT) {
        float s = fc3b[tid];
        #pragma unroll
        for (int kc2 = 0; kc2 < 16; ++kc2) s += part[tid][kc2];
        predv = s;
        out[(w*TT + t)*NOUT + tid] = s;
      }
      if (tid < 64) {
        float v  = (tid < 32) ? predv : -1e30f;
        int  idx = tid;
        #pragma unroll
        for (int off = 32; off > 0; off >>= 1) {
          float ov = __shfl_xor(v, off);
          int   oi = __shfl_xor(idx, off);
          if (ov > v || (ov == v && oi < idx)) { v = ov; idx = oi; }
        }
        if (tid == 0) lds_act = idx;
      }
      __syncthreads();
      const int act = lds_act;
      if (tid < 512) xbuf[tid*BB + w] = (tid < 511) ? emb[act*(HH-1) + tid] : 1.0f;
    }
    gbar(bar, ep++, grp);
  }

  // ---- postprocess row w ----
  if (tid < TT) {
    const int s = tid;
    float* po = out + (w*TT + s)*NOUT;
    float v[NOUT];
    #pragma unroll
    for (int o = 0; o < NOUT; ++o) v[o] = po[o];
    float m = v[0];
    #pragma unroll
    for (int o = 1; o < 32; ++o) m = fmaxf(m, v[o]);
    float sum = 0.0f;
    #pragma unroll
    for (int o = 0; o < 32; ++o) sum += expf(v[o] - m);
    float lse = m + logf(sum);
    #pragma unroll
    for (int o = 0; o < 32; ++o) po[o] = v[o] - lse;
    float d = v[32];
    float dm = d;
    #pragma unroll
    for (int off = 32; off > 0; off >>= 1) dm = fmaxf(dm, __shfl_xor(dm, off));
    float e = expf(d - dm);
    float es = e;
    #pragma unroll
    for (int off = 32; off > 0; off >>= 1) es += __shfl_xor(es, off);
    po[32] = e / es;
  }
}

extern "C" void kernel_launch(void* const* d_in, const int* in_sizes, int n_in,
                              void* d_out, int out_size, void* d_ws, size_t ws_size,
                              hipStream_t stream) {
  const float* h0   = (const float*)d_in[1];
  const float* c0   = (const float*)d_in[2];
  const float* cnd  = (const float*)d_in[3];
  const float* emb  = (const float*)d_in[4];
  const float* Wih  = (const float*)d_in[5];
  const float* Whh  = (const float*)d_in[6];
  const float* bih  = (const float*)d_in[7];
  const float* bhh  = (const float*)d_in[8];
  const float* fcW  = (const float*)d_in[9];
  const float* fcb  = (const float*)d_in[10];
  const float* fc2W = (const float*)d_in[11];
  const float* fc2b = (const float*)d_in[12];
  const float* fc3W = (const float*)d_in[13];
  const float* fc3b = (const float*)d_in[14];

  unsigned* bar = (unsigned*)d_ws;
  float* wsf = (float*)((char*)d_ws + 1024);
  float* wsT = wsf + 10*SZ;   // 16MB weight block area

  (void)hipMemsetAsync(d_ws, 0, 1024, stream);

  hipLaunchKernelGGL(transpose_weights, dim3(NWG), dim3(256), 0, stream,
                     Wih, Whh, wsT);
  hipLaunchKernelGGL(decoder_kernel, dim3(NWG), dim3(NTHR), 0, stream,
                     h0, c0, cnd, emb, wsT, bih, bhh, fcW, fcb,
                     fc2W, fc2b, fc3W, fc3b, (float*)d_out, bar, wsf);
}

// Round 10
// 5514.326 us; speedup vs baseline: 2.1257x; 2.1257x over previous
//
#include <hip/hip_runtime.h>
#include <math.h>

#define BB   256   // batch
#define HH   512   // hidden
#define NWG  256
#define NTHR 1024
#define TT   64    // steps
#define NOUT 33
#define CD   128   // cond dim
#define SZ   (HH*BB)
#define LOFF (4*HH*HH)   // layer stride in Wih/Whh
#define BOFF (4*HH)      // layer stride in bih/bhh
#define WBLK (16*1024)   // floats per WG in wsT: [1024 k][16 slots]

typedef float f16v __attribute__((ext_vector_type(16)));
typedef float f8v  __attribute__((ext_vector_type(8)));
typedef const __attribute__((address_space(4))) float  cfloat;
typedef const __attribute__((address_space(4))) f16v   cf16v;
typedef const __attribute__((address_space(4))) f8v    cf8v;

__device__ __forceinline__ float sigm(float x)  { return 1.0f/(1.0f+expf(-x)); }
__device__ __forceinline__ float lrelu(float x) { return x >= 0.0f ? x : 0.01f*x; }

// Wave-uniform pointer, provably uniform, in the constant address space:
// uniform AS4 loads select to s_load_* (scalar pipe, broadcast for free).
__device__ __forceinline__ cfloat* cptr(const float* p) {
  unsigned long long u = (unsigned long long)p;
  unsigned lo = __builtin_amdgcn_readfirstlane((unsigned)u);
  unsigned hi = __builtin_amdgcn_readfirstlane((unsigned)(u >> 32));
  return (cfloat*)((((unsigned long long)hi) << 32) | (unsigned long long)lo);
}

// Monotonic 2-level grid barrier.
__device__ __forceinline__ void gbar(unsigned* bar, unsigned ep, int grp) {
  __syncthreads();
  if (threadIdx.x == 0) {
    __builtin_amdgcn_fence(__ATOMIC_RELEASE, "agent");
    unsigned old = __hip_atomic_fetch_add(&bar[grp*16], 1u, __ATOMIC_RELAXED, __HIP_MEMORY_SCOPE_AGENT);
    if (old == ep*32u + 31u) {
      unsigned o2 = __hip_atomic_fetch_add(&bar[128], 1u, __ATOMIC_RELAXED, __HIP_MEMORY_SCOPE_AGENT);
      if (o2 == ep*8u + 7u)
        __hip_atomic_store(&bar[144], ep+1u, __ATOMIC_RELAXED, __HIP_MEMORY_SCOPE_AGENT);
    }
    while (__hip_atomic_load(&bar[144], __ATOMIC_RELAXED, __HIP_MEMORY_SCOPE_AGENT) < ep+1u)
      __builtin_amdgcn_s_sleep(1);
    __builtin_amdgcn_fence(__ATOMIC_ACQUIRE, "agent");
  }
  __syncthreads();
}

// Pre-kernel: weights -> [k][16] blocks (64B/k) for s_load_dwordx16.
extern "C" __global__ void __launch_bounds__(256)
transpose_weights(const float* __restrict__ Wih, const float* __restrict__ Whh,
                  float* __restrict__ wsT)
{
  const int w   = blockIdx.x;
  const int tid = threadIdx.x;
  float* dst = wsT + w*WBLK;
  #pragma unroll 1
  for (int j = 0; j < 64; ++j) {
    int i  = j*256 + tid;        // i = ri*1024 + k
    int ri = i >> 10, k = i & 1023;
    int l  = k >> 9,  kk = k & 511;
    int r2 = ri & 7,  u = r2 >> 2, g = r2 & 3;
    const float* src = (ri < 8) ? Wih : Whh;
    dst[k*16 + ri] = src[l*LOFF + (g*HH + 2*w + u)*HH + kk];
  }
}

// One k of gate GEMM for 2 batch cols: w = [Wi r0..7 | Wh r0..7] (SGPRs).
__device__ __forceinline__ void FMA2(const f16v& w, float x0, float x1,
                                     float h0, float h1, float* acc) {
  #pragma unroll
  for (int r = 0; r < 8; ++r) {
    acc[r*2+0] += w[r]*x0;
    acc[r*2+1] += w[r]*x1;
  }
  #pragma unroll
  for (int r = 0; r < 8; ++r) {
    acc[r*2+0] += w[8+r]*h0;
    acc[r*2+1] += w[8+r]*h1;
  }
}

// LSTM layer phase. Wave = (bg, ks): lane owns batch cols b0,b0+64; 8 gate rows;
// 64-k slice. Weights via compiler-managed scalar loads (AS4), acts prefetched.
__device__ __forceinline__ void lstm_phase(const float* __restrict__ wT,
    const float* __restrict__ bias, float* __restrict__ red,
    const float* __restrict__ xsrc, const float* __restrict__ hsrc,
    float* __restrict__ hdst, float* __restrict__ cbuf,
    int hu0, int tid, int ks, int bg)
{
  const int lane  = tid & 63;
  const int kbase = ks*64;
  const int b0    = bg*128 + lane;
  cf16v* wk = (cf16v*)cptr(wT + kbase*16);   // [k][16] 64B chunks
  const float* xp = xsrc + kbase*BB + b0;
  const float* hp = hsrc + kbase*BB + b0;

  float acc[16];
  #pragma unroll
  for (int r = 0; r < 16; ++r) acc[r] = 0.0f;

  float qx[4], qh[4], px[4], ph[4];   // [k2*2 + col]
  #pragma unroll
  for (int j = 0; j < 2; ++j) {
    qx[j*2] = xp[j*BB]; qx[j*2+1] = xp[j*BB + 64];
    qh[j*2] = hp[j*BB]; qh[j*2+1] = hp[j*BB + 64];
  }
  #pragma unroll 1
  for (int it = 0; it < 32; ++it) {
    f16v w0 = wk[it*2+0];
    f16v w1 = wk[it*2+1];
    if (it+1 < 32) {
      #pragma unroll
      for (int j = 0; j < 2; ++j) {
        px[j*2]   = xp[(it*2+2+j)*BB];      px[j*2+1] = xp[(it*2+2+j)*BB + 64];
        ph[j*2]   = hp[(it*2+2+j)*BB];      ph[j*2+1] = hp[(it*2+2+j)*BB + 64];
      }
    }
    FMA2(w0, qx[0], qx[1], qh[0], qh[1], acc);
    FMA2(w1, qx[2], qx[3], qh[2], qh[3], acc);
    #pragma unroll
    for (int j = 0; j < 4; ++j) { qx[j] = px[j]; qh[j] = ph[j]; }
  }
  #pragma unroll
  for (int r = 0; r < 8; ++r) {
    red[(ks*8 + r)*BB + b0]      = acc[r*2];
    red[(ks*8 + r)*BB + b0 + 64] = acc[r*2+1];
  }
  __syncthreads();
  if (tid < 512) {
    const int b = tid & 255, u = tid >> 8;
    float g[4];
    #pragma unroll
    for (int gg = 0; gg < 4; ++gg) {
      float s = bias[u*4+gg];
      #pragma unroll
      for (int k2 = 0; k2 < 8; ++k2) s += red[(k2*8 + u*4+gg)*BB + b];
      g[gg] = s;
    }
    const int hu = hu0 + u;
    float ig = sigm(g[0]), fg = sigm(g[1]);
    float gv = tanhf(g[2]), og = sigm(g[3]);
    float cn = fg*cbuf[hu*BB+b] + ig*gv;
    cbuf[hu*BB+b] = cn;
    hdst[hu*BB+b] = og*tanhf(cn);
  }
}

extern "C" __global__ void __launch_bounds__(NTHR)
decoder_kernel(const float* __restrict__ h0, const float* __restrict__ c0,
               const float* __restrict__ conds, const float* __restrict__ emb,
               const float* __restrict__ wsT, const float* __restrict__ bih,
               const float* __restrict__ bhh, const float* __restrict__ fcW,
               const float* __restrict__ fcb, const float* __restrict__ fc2W,
               const float* __restrict__ fc2b, const float* __restrict__ fc3W,
               const float* __restrict__ fc3b,
               float* __restrict__ out, unsigned* bar, float* wsf)
{
  const int w   = blockIdx.x;
  const int tid = threadIdx.x;
  const int hu0 = 2*w;
  const int grp = w & 7;
  const int wv  = tid >> 6;        // wave 0..15
  const int bg  = wv & 1;          // batch half
  const int ks  = wv >> 1;         // k-slice 0..7

  float* xbuf  = wsf;
  float* h1b0  = wsf + 1*SZ;
  float* h1b1  = wsf + 2*SZ;
  float* h2b0  = wsf + 3*SZ;
  float* h2b1  = wsf + 4*SZ;
  float* c1b   = wsf + 5*SZ;
  float* c2b   = wsf + 6*SZ;
  float* condb = wsf + 7*SZ;
  float* yb    = wsf + 8*SZ;
  float* condY = wsf + 9*SZ;

  const float* wT1 = wsT + w*WBLK;            // layer 0: k 0..511
  const float* wT2 = wsT + w*WBLK + 512*16;   // layer 1: k 512..1023

  __shared__ float red[64*BB];     // 64KB reduction scratch
  __shared__ float bias1[8], bias2[8], biasc[2];
  __shared__ float lds_y[HH];
  __shared__ float part[NOUT][17];
  __shared__ int   lds_act;
  __shared__ float lds_pad[4096];  // LDS > 80KB -> exactly 1 WG/CU
  if (tid == 0) ((volatile float*)lds_pad)[0] = 0.0f;

  // ---- init ----
  if (tid < 512) {
    const int b = tid & 255, u = tid >> 8;
    const int k = hu0 + u;
    xbuf[k*BB+b] = (k < HH-1) ? emb[k] : 0.0f;   // emb[SOS=0][k], dur=0
    h1b0[k*BB+b] = h0[b*HH + k];
    c1b [k*BB+b] = c0[b*HH + k];
    h2b0[k*BB+b] = h0[(BB+b)*HH + k];
    c2b [k*BB+b] = c0[(BB+b)*HH + k];
    float a = fcb[k];
    const float4* cp = (const float4*)(conds + b*CD);
    const float4* wp = (const float4*)(fcW + k*CD);
    #pragma unroll 8
    for (int q = 0; q < CD/4; ++q) {
      float4 c4 = cp[q], w4 = wp[q];
      a += c4.x*w4.x + c4.y*w4.y + c4.z*w4.z + c4.w*w4.w;
    }
    condb[k*BB+b] = lrelu(a);
  }
  if (tid < 8) {
    int u = tid >> 2, g = tid & 3;
    bias1[tid] = bih[g*HH + hu0 + u] + bhh[g*HH + hu0 + u];
    bias2[tid] = bih[BOFF + g*HH + hu0 + u] + bhh[BOFF + g*HH + hu0 + u];
  }
  if (tid < 2) biasc[tid] = fc2b[hu0 + tid];

  unsigned ep = 0;
  gbar(bar, ep++, grp);

  // condY[hu][b]: cond-branch through fc2 (step-invariant)
  if (tid < 512) {
    const int b = tid & 255, u = tid >> 8;
    cfloat* wr = cptr(fc2W + (hu0+u)*HH);
    float s = 0.0f;
    #pragma unroll 4
    for (int k = 0; k < HH; k += 4) {
      s += wr[k]*condb[k*BB+b]     + wr[k+1]*condb[(k+1)*BB+b]
         + wr[k+2]*condb[(k+2)*BB+b] + wr[k+3]*condb[(k+3)*BB+b];
    }
    condY[(hu0+u)*BB + b] = s;
  }
  __syncthreads();

  for (int t = 0; t < TT; ++t) {
    const bool par = (t & 1) != 0;
    float* h1r = par ? h1b1 : h1b0;
    float* h1w = par ? h1b0 : h1b1;
    float* h2r = par ? h2b1 : h2b0;
    float* h2w = par ? h2b0 : h2b1;

    // Phase A: layer 0
    lstm_phase(wT1, bias1, red, xbuf, h1r, h1w, c1b, hu0, tid, ks, bg);
    gbar(bar, ep++, grp);
    // Phase B: layer 1
    lstm_phase(wT2, bias2, red, h1w, h2r, h2w, c2b, hu0, tid, ks, bg);
    gbar(bar, ep++, grp);
    // Phase C: y rows hu0,hu0+1; fc2 row-pair via scalar pipe
    {
      const int b = tid & 255, s4 = tid >> 8;   // s4: k-slice of 128
      const float* hp = h2w + (s4*128)*BB + b;
      cf8v* w0v = (cf8v*)cptr(fc2W + (hu0+0)*HH + s4*128);
      cf8v* w1v = (cf8v*)cptr(fc2W + (hu0+1)*HH + s4*128);
      float a0 = 0.0f, a1 = 0.0f;
      float q[8], pq[8];
      #pragma unroll
      for (int j = 0; j < 8; ++j) q[j] = hp[j*BB];
      #pragma unroll 1
      for (int it = 0; it < 16; ++it) {
        f8v wa = w0v[it];
        f8v wb = w1v[it];
        if (it+1 < 16) {
          #pragma unroll
          for (int j = 0; j < 8; ++j) pq[j] = hp[(it*8+8+j)*BB];
        }
        #pragma unroll
        for (int j = 0; j < 8; ++j) { a0 += wa[j]*q[j]; a1 += wb[j]*q[j]; }
        #pragma unroll
        for (int j = 0; j < 8; ++j) q[j] = pq[j];
      }
      red[(s4*2+0)*BB + b] = a0;
      red[(s4*2+1)*BB + b] = a1;
    }
    __syncthreads();
    if (tid < 512) {
      const int b = tid & 255, u = tid >> 8;
      float s = biasc[u] + condY[(hu0+u)*BB + b];
      #pragma unroll
      for (int s4 = 0; s4 < 4; ++s4) s += red[(s4*2+u)*BB + b];
      yb[(hu0+u)*BB + b] = lrelu(s);
    }
    gbar(bar, ep++, grp);
    // Phase D: WG w handles batch row w: fc3, argmax, next x
    {
      if (tid < 512) lds_y[tid] = yb[tid*BB + w];
      __syncthreads();
      int o = 0, kc = 0;
      bool active = false;
      if (tid < 512)        { o = tid & 31; kc = tid >> 5; active = true; }
      else if (tid < 528)   { o = 32;       kc = tid - 512; active = true; }
      if (active) {
        float p = 0.0f;
        const float* fw = fc3W + o*HH + kc*32;
        #pragma unroll
        for (int k2 = 0; k2 < 32; ++k2) p += fw[k2] * lds_y[kc*32 + k2];
        part[o][kc] = p;
      }
      __syncthreads();
      float predv = -1e30f;
      if (tid < NOUT) {
        float s = fc3b[tid];
        #pragma unroll
        for (int kc2 = 0; kc2 < 16; ++kc2) s += part[tid][kc2];
        predv = s;
        out[(w*TT + t)*NOUT + tid] = s;
      }
      if (tid < 64) {
        float v  = (tid < 32) ? predv : -1e30f;
        int  idx = tid;
        #pragma unroll
        for (int off = 32; off > 0; off >>= 1) {
          float ov = __shfl_xor(v, off);
          int   oi = __shfl_xor(idx, off);
          if (ov > v || (ov == v && oi < idx)) { v = ov; idx = oi; }
        }
        if (tid == 0) lds_act = idx;
      }
      __syncthreads();
      const int act = lds_act;
      if (tid < 512) xbuf[tid*BB + w] = (tid < 511) ? emb[act*(HH-1) + tid] : 1.0f;
    }
    gbar(bar, ep++, grp);
  }

  // ---- postprocess row w ----
  if (tid < TT) {
    const int s = tid;
    float* po = out + (w*TT + s)*NOUT;
    float v[NOUT];
    #pragma unroll
    for (int o = 0; o < NOUT; ++o) v[o] = po[o];
    float m = v[0];
    #pragma unroll
    for (int o = 1; o < 32; ++o) m = fmaxf(m, v[o]);
    float sum = 0.0f;
    #pragma unroll
    for (int o = 0; o < 32; ++o) sum += expf(v[o] - m);
    float lse = m + logf(sum);
    #pragma unroll
    for (int o = 0; o < 32; ++o) po[o] = v[o] - lse;
    float d = v[32];
    float dm = d;
    #pragma unroll
    for (int off = 32; off > 0; off >>= 1) dm = fmaxf(dm, __shfl_xor(dm, off));
    float e = expf(d - dm);
    float es = e;
    #pragma unroll
    for (int off = 32; off > 0; off >>= 1) es += __shfl_xor(es, off);
    po[32] = e / es;
  }
}

extern "C" void kernel_launch(void* const* d_in, const int* in_sizes, int n_in,
                              void* d_out, int out_size, void* d_ws, size_t ws_size,
                              hipStream_t stream) {
  const float* h0   = (const float*)d_in[1];
  const float* c0   = (const float*)d_in[2];
  const float* cnd  = (const float*)d_in[3];
  const float* emb  = (const float*)d_in[4];
  const float* Wih  = (const float*)d_in[5];
  const float* Whh  = (const float*)d_in[6];
  const float* bih  = (const float*)d_in[7];
  const float* bhh  = (const float*)d_in[8];
  const float* fcW  = (const float*)d_in[9];
  const float* fcb  = (const float*)d_in[10];
  const float* fc2W = (const float*)d_in[11];
  const float* fc2b = (const float*)d_in[12];
  const float* fc3W = (const float*)d_in[13];
  const float* fc3b = (const float*)d_in[14];

  unsigned* bar = (unsigned*)d_ws;
  float* wsf = (float*)((char*)d_ws + 1024);
  float* wsT = wsf + 10*SZ;   // 16MB weight block area

  (void)hipMemsetAsync(d_ws, 0, 1024, stream);

  hipLaunchKernelGGL(transpose_weights, dim3(NWG), dim3(256), 0, stream,
                     Wih, Whh, wsT);
  hipLaunchKernelGGL(decoder_kernel, dim3(NWG), dim3(NTHR), 0, stream,
                     h0, c0, cnd, emb, wsT, bih, bhh, fcW, fcb,
                     fc2W, fc2b, fc3W, fc3b, (float*)d_out, bar, wsf);
}

// Round 11
// 3731.009 us; speedup vs baseline: 3.1417x; 1.4780x over previous
//
#include <hip/hip_runtime.h>
#include <math.h>

#define BB   256   // batch
#define HH   512   // hidden
#define NWG  256
#define NTHR 1024
#define TT   64    // steps
#define NOUT 33
#define CD   128   // cond dim
#define SZ   (HH*BB)
#define LOFF (4*HH*HH)   // layer stride in Wih/Whh
#define BOFF (4*HH)      // layer stride in bih/bhh
#define WBLK (16*1024)   // floats per WG in wsT: [1024 k][16 slots]

typedef float f16v __attribute__((ext_vector_type(16)));
typedef float f8v  __attribute__((ext_vector_type(8)));
typedef const __attribute__((address_space(4))) float  cfloat;
typedef const __attribute__((address_space(4))) f16v   cf16v;
typedef const __attribute__((address_space(4))) f8v    cf8v;

__device__ __forceinline__ float sigm(float x)  { return 1.0f/(1.0f+expf(-x)); }
__device__ __forceinline__ float lrelu(float x) { return x >= 0.0f ? x : 0.01f*x; }

// Memory-side coherent (cross-XCD) scalar access: bypasses L1/L2, no fence needed.
__device__ __forceinline__ float gld(const float* p) {
  return __hip_atomic_load(p, __ATOMIC_RELAXED, __HIP_MEMORY_SCOPE_AGENT);
}
__device__ __forceinline__ void gst(float* p, float v) {
  __hip_atomic_store(p, v, __ATOMIC_RELAXED, __HIP_MEMORY_SCOPE_AGENT);
}

// Wave-uniform pointer, provably uniform, in the constant address space:
// uniform AS4 loads select to s_load_* (scalar pipe, broadcast for free).
__device__ __forceinline__ cfloat* cptr(const float* p) {
  unsigned long long u = (unsigned long long)p;
  unsigned lo = __builtin_amdgcn_readfirstlane((unsigned)u);
  unsigned hi = __builtin_amdgcn_readfirstlane((unsigned)(u >> 32));
  return (cfloat*)((((unsigned long long)hi) << 32) | (unsigned long long)lo);
}

// Monotonic 2-level grid barrier. fence=true only for the init barrier
// (normally-written init state needs L2 writeback + invalidate once).
// Steady-state barriers carry NO cache maintenance: all exchanged data moves
// via sc (memory-side) loads/stores, so L2-resident weights stay warm.
__device__ __forceinline__ void gbar(unsigned* bar, unsigned ep, int grp, bool fence) {
  __syncthreads();   // drains vmcnt/lgkmcnt for all lanes before arrival
  if (threadIdx.x == 0) {
    if (fence) __builtin_amdgcn_fence(__ATOMIC_RELEASE, "agent");
    unsigned old = __hip_atomic_fetch_add(&bar[grp*16], 1u, __ATOMIC_RELAXED, __HIP_MEMORY_SCOPE_AGENT);
    if (old == ep*32u + 31u) {
      unsigned o2 = __hip_atomic_fetch_add(&bar[128], 1u, __ATOMIC_RELAXED, __HIP_MEMORY_SCOPE_AGENT);
      if (o2 == ep*8u + 7u)
        __hip_atomic_store(&bar[144], ep+1u, __ATOMIC_RELAXED, __HIP_MEMORY_SCOPE_AGENT);
    }
    while (__hip_atomic_load(&bar[144], __ATOMIC_RELAXED, __HIP_MEMORY_SCOPE_AGENT) < ep+1u)
      __builtin_amdgcn_s_sleep(1);
    if (fence) __builtin_amdgcn_fence(__ATOMIC_ACQUIRE, "agent");
  }
  __syncthreads();
}

// Pre-kernel: weights -> [k][16] blocks (64B/k) for s_load_dwordx16.
extern "C" __global__ void __launch_bounds__(256)
transpose_weights(const float* __restrict__ Wih, const float* __restrict__ Whh,
                  float* __restrict__ wsT)
{
  const int w   = blockIdx.x;
  const int tid = threadIdx.x;
  float* dst = wsT + w*WBLK;
  #pragma unroll 1
  for (int j = 0; j < 64; ++j) {
    int i  = j*256 + tid;        // i = ri*1024 + k
    int ri = i >> 10, k = i & 1023;
    int l  = k >> 9,  kk = k & 511;
    int r2 = ri & 7,  u = r2 >> 2, g = r2 & 3;
    const float* src = (ri < 8) ? Wih : Whh;
    dst[k*16 + ri] = src[l*LOFF + (g*HH + 2*w + u)*HH + kk];
  }
}

// One k of gate GEMM for 2 batch cols: w = [Wi r0..7 | Wh r0..7] (SGPRs).
__device__ __forceinline__ void FMA2(const f16v& w, float x0, float x1,
                                     float h0, float h1, float* acc) {
  #pragma unroll
  for (int r = 0; r < 8; ++r) {
    acc[r*2+0] += w[r]*x0;
    acc[r*2+1] += w[r]*x1;
  }
  #pragma unroll
  for (int r = 0; r < 8; ++r) {
    acc[r*2+0] += w[8+r]*h0;
    acc[r*2+1] += w[8+r]*h1;
  }
}

// LSTM layer phase. Wave = (bg, ks): lane owns batch cols b0,b0+64; 8 gate rows;
// 64-k slice. Weights via compiler-managed scalar loads (AS4, L2-resident);
// activations via sc loads (memory-side coherent), prefetched 1 group ahead.
__device__ __forceinline__ void lstm_phase(const float* __restrict__ wT,
    const float* __restrict__ bias, float* __restrict__ red,
    const float* __restrict__ xsrc, const float* __restrict__ hsrc,
    float* __restrict__ hdst, float* __restrict__ cbuf,
    int hu0, int tid, int ks, int bg)
{
  const int lane  = tid & 63;
  const int kbase = ks*64;
  const int b0    = bg*128 + lane;
  cf16v* wk = (cf16v*)cptr(wT + kbase*16);   // [k][16] 64B chunks
  const float* xp = xsrc + kbase*BB + b0;
  const float* hp = hsrc + kbase*BB + b0;

  float acc[16];
  #pragma unroll
  for (int r = 0; r < 16; ++r) acc[r] = 0.0f;

  float qx[4], qh[4], px[4], ph[4];   // [k2*2 + col]
  #pragma unroll
  for (int j = 0; j < 2; ++j) {
    qx[j*2] = gld(xp + j*BB); qx[j*2+1] = gld(xp + j*BB + 64);
    qh[j*2] = gld(hp + j*BB); qh[j*2+1] = gld(hp + j*BB + 64);
  }
  #pragma unroll 1
  for (int it = 0; it < 32; ++it) {
    f16v w0 = wk[it*2+0];
    f16v w1 = wk[it*2+1];
    if (it+1 < 32) {
      #pragma unroll
      for (int j = 0; j < 2; ++j) {
        px[j*2]   = gld(xp + (it*2+2+j)*BB);  px[j*2+1] = gld(xp + (it*2+2+j)*BB + 64);
        ph[j*2]   = gld(hp + (it*2+2+j)*BB);  ph[j*2+1] = gld(hp + (it*2+2+j)*BB + 64);
      }
    }
    FMA2(w0, qx[0], qx[1], qh[0], qh[1], acc);
    FMA2(w1, qx[2], qx[3], qh[2], qh[3], acc);
    #pragma unroll
    for (int j = 0; j < 4; ++j) { qx[j] = px[j]; qh[j] = ph[j]; }
  }
  #pragma unroll
  for (int r = 0; r < 8; ++r) {
    red[(ks*8 + r)*BB + b0]      = acc[r*2];
    red[(ks*8 + r)*BB + b0 + 64] = acc[r*2+1];
  }
  __syncthreads();
  if (tid < 512) {
    const int b = tid & 255, u = tid >> 8;
    float g[4];
    #pragma unroll
    for (int gg = 0; gg < 4; ++gg) {
      float s = bias[u*4+gg];
      #pragma unroll
      for (int k2 = 0; k2 < 8; ++k2) s += red[(k2*8 + u*4+gg)*BB + b];
      g[gg] = s;
    }
    const int hu = hu0 + u;
    float ig = sigm(g[0]), fg = sigm(g[1]);
    float gv = tanhf(g[2]), og = sigm(g[3]);
    float cn = fg*cbuf[hu*BB+b] + ig*gv;     // c is WG-private: normal
    cbuf[hu*BB+b] = cn;
    gst(hdst + hu*BB + b, og*tanhf(cn));     // h is exchanged: sc store
  }
}

extern "C" __global__ void __launch_bounds__(NTHR)
decoder_kernel(const float* __restrict__ h0, const float* __restrict__ c0,
               const float* __restrict__ conds, const float* __restrict__ emb,
               const float* __restrict__ wsT, const float* __restrict__ bih,
               const float* __restrict__ bhh, const float* __restrict__ fcW,
               const float* __restrict__ fcb, const float* __restrict__ fc2W,
               const float* __restrict__ fc2b, const float* __restrict__ fc3W,
               const float* __restrict__ fc3b,
               float* __restrict__ out, unsigned* bar, float* wsf)
{
  const int w   = blockIdx.x;
  const int tid = threadIdx.x;
  const int hu0 = 2*w;
  const int grp = w & 7;
  const int wv  = tid >> 6;        // wave 0..15
  const int bg  = wv & 1;          // batch half
  const int ks  = wv >> 1;         // k-slice 0..7

  float* xbuf  = wsf;
  float* h1b0  = wsf + 1*SZ;
  float* h1b1  = wsf + 2*SZ;
  float* h2b0  = wsf + 3*SZ;
  float* h2b1  = wsf + 4*SZ;
  float* c1b   = wsf + 5*SZ;
  float* c2b   = wsf + 6*SZ;
  float* condb = wsf + 7*SZ;
  float* yb    = wsf + 8*SZ;
  float* condY = wsf + 9*SZ;

  const float* wT1 = wsT + w*WBLK;            // layer 0: k 0..511
  const float* wT2 = wsT + w*WBLK + 512*16;   // layer 1: k 512..1023

  __shared__ float red[64*BB];     // 64KB reduction scratch
  __shared__ float bias1[8], bias2[8], biasc[2];
  __shared__ float lds_y[HH];
  __shared__ float part[NOUT][17];
  __shared__ int   lds_act;
  __shared__ float lds_pad[4096];  // LDS > 80KB -> exactly 1 WG/CU
  if (tid == 0) ((volatile float*)lds_pad)[0] = 0.0f;

  // ---- init (normal stores; made visible by the one full-fence barrier) ----
  if (tid < 512) {
    const int b = tid & 255, u = tid >> 8;
    const int k = hu0 + u;
    xbuf[k*BB+b] = (k < HH-1) ? emb[k] : 0.0f;   // emb[SOS=0][k], dur=0
    h1b0[k*BB+b] = h0[b*HH + k];
    c1b [k*BB+b] = c0[b*HH + k];
    h2b0[k*BB+b] = h0[(BB+b)*HH + k];
    c2b [k*BB+b] = c0[(BB+b)*HH + k];
    float a = fcb[k];
    const float4* cp = (const float4*)(conds + b*CD);
    const float4* wp = (const float4*)(fcW + k*CD);
    #pragma unroll 8
    for (int q = 0; q < CD/4; ++q) {
      float4 c4 = cp[q], w4 = wp[q];
      a += c4.x*w4.x + c4.y*w4.y + c4.z*w4.z + c4.w*w4.w;
    }
    condb[k*BB+b] = lrelu(a);
  }
  if (tid < 8) {
    int u = tid >> 2, g = tid & 3;
    bias1[tid] = bih[g*HH + hu0 + u] + bhh[g*HH + hu0 + u];
    bias2[tid] = bih[BOFF + g*HH + hu0 + u] + bhh[BOFF + g*HH + hu0 + u];
  }
  if (tid < 2) biasc[tid] = fc2b[hu0 + tid];

  unsigned ep = 0;
  gbar(bar, ep++, grp, true);   // FULL fence once: flush init writes, inv caches

  // condY[hu][b]: cond-branch through fc2 (step-invariant, WG-private output)
  if (tid < 512) {
    const int b = tid & 255, u = tid >> 8;
    cfloat* wr = cptr(fc2W + (hu0+u)*HH);
    float s = 0.0f;
    #pragma unroll 4
    for (int k = 0; k < HH; k += 4) {
      s += wr[k]*condb[k*BB+b]     + wr[k+1]*condb[(k+1)*BB+b]
         + wr[k+2]*condb[(k+2)*BB+b] + wr[k+3]*condb[(k+3)*BB+b];
    }
    condY[(hu0+u)*BB + b] = s;
  }
  __syncthreads();

  for (int t = 0; t < TT; ++t) {
    const bool par = (t & 1) != 0;
    float* h1r = par ? h1b1 : h1b0;
    float* h1w = par ? h1b0 : h1b1;
    float* h2r = par ? h2b1 : h2b0;
    float* h2w = par ? h2b0 : h2b1;

    // Phase A: layer 0
    lstm_phase(wT1, bias1, red, xbuf, h1r, h1w, c1b, hu0, tid, ks, bg);
    gbar(bar, ep++, grp, false);
    // Phase B: layer 1
    lstm_phase(wT2, bias2, red, h1w, h2r, h2w, c2b, hu0, tid, ks, bg);
    gbar(bar, ep++, grp, false);
    // Phase C: y rows hu0,hu0+1; fc2 row-pair via scalar pipe
    {
      const int b = tid & 255, s4 = tid >> 8;   // s4: k-slice of 128
      const float* hp = h2w + (s4*128)*BB + b;
      cf8v* w0v = (cf8v*)cptr(fc2W + (hu0+0)*HH + s4*128);
      cf8v* w1v = (cf8v*)cptr(fc2W + (hu0+1)*HH + s4*128);
      float a0 = 0.0f, a1 = 0.0f;
      float q[8], pq[8];
      #pragma unroll
      for (int j = 0; j < 8; ++j) q[j] = gld(hp + j*BB);
      #pragma unroll 1
      for (int it = 0; it < 16; ++it) {
        f8v wa = w0v[it];
        f8v wb = w1v[it];
        if (it+1 < 16) {
          #pragma unroll
          for (int j = 0; j < 8; ++j) pq[j] = gld(hp + (it*8+8+j)*BB);
        }
        #pragma unroll
        for (int j = 0; j < 8; ++j) { a0 += wa[j]*q[j]; a1 += wb[j]*q[j]; }
        #pragma unroll
        for (int j = 0; j < 8; ++j) q[j] = pq[j];
      }
      red[(s4*2+0)*BB + b] = a0;
      red[(s4*2+1)*BB + b] = a1;
    }
    __syncthreads();
    if (tid < 512) {
      const int b = tid & 255, u = tid >> 8;
      float s = biasc[u] + condY[(hu0+u)*BB + b];
      #pragma unroll
      for (int s4 = 0; s4 < 4; ++s4) s += red[(s4*2+u)*BB + b];
      gst(yb + (hu0+u)*BB + b, lrelu(s));    // exchanged: sc store
    }
    gbar(bar, ep++, grp, false);
    // Phase D: WG w handles batch row w: fc3, argmax, next x
    {
      if (tid < 512) lds_y[tid] = gld(yb + tid*BB + w);
      __syncthreads();
      int o = 0, kc = 0;
      bool active = false;
      if (tid < 512)        { o = tid & 31; kc = tid >> 5; active = true; }
      else if (tid < 528)   { o = 32;       kc = tid - 512; active = true; }
      if (active) {
        float p = 0.0f;
        const float* fw = fc3W + o*HH + kc*32;
        #pragma unroll
        for (int k2 = 0; k2 < 32; ++k2) p += fw[k2] * lds_y[kc*32 + k2];
        part[o][kc] = p;
      }
      __syncthreads();
      float predv = -1e30f;
      if (tid < NOUT) {
        float s = fc3b[tid];
        #pragma unroll
        for (int kc2 = 0; kc2 < 16; ++kc2) s += part[tid][kc2];
        predv = s;
        out[(w*TT + t)*NOUT + tid] = s;      // WG-private until kernel end
      }
      if (tid < 64) {
        float v  = (tid < 32) ? predv : -1e30f;
        int  idx = tid;
        #pragma unroll
        for (int off = 32; off > 0; off >>= 1) {
          float ov = __shfl_xor(v, off);
          int   oi = __shfl_xor(idx, off);
          if (ov > v || (ov == v && oi < idx)) { v = ov; idx = oi; }
        }
        if (tid == 0) lds_act = idx;
      }
      __syncthreads();
      const int act = lds_act;
      if (tid < 512)
        gst(xbuf + tid*BB + w, (tid < 511) ? emb[act*(HH-1) + tid] : 1.0f);
    }
    gbar(bar, ep++, grp, false);
  }

  // ---- postprocess row w (out is WG-private) ----
  if (tid < TT) {
    const int s = tid;
    float* po = out + (w*TT + s)*NOUT;
    float v[NOUT];
    #pragma unroll
    for (int o = 0; o < NOUT; ++o) v[o] = po[o];
    float m = v[0];
    #pragma unroll
    for (int o = 1; o < 32; ++o) m = fmaxf(m, v[o]);
    float sum = 0.0f;
    #pragma unroll
    for (int o = 0; o < 32; ++o) sum += expf(v[o] - m);
    float lse = m + logf(sum);
    #pragma unroll
    for (int o = 0; o < 32; ++o) po[o] = v[o] - lse;
    float d = v[32];
    float dm = d;
    #pragma unroll
    for (int off = 32; off > 0; off >>= 1) dm = fmaxf(dm, __shfl_xor(dm, off));
    float e = expf(d - dm);
    float es = e;
    #pragma unroll
    for (int off = 32; off > 0; off >>= 1) es += __shfl_xor(es, off);
    po[32] = e / es;
  }
}

extern "C" void kernel_launch(void* const* d_in, const int* in_sizes, int n_in,
                              void* d_out, int out_size, void* d_ws, size_t ws_size,
                              hipStream_t stream) {
  const float* h0   = (const float*)d_in[1];
  const float* c0   = (const float*)d_in[2];
  const float* cnd  = (const float*)d_in[3];
  const float* emb  = (const float*)d_in[4];
  const float* Wih  = (const float*)d_in[5];
  const float* Whh  = (const float*)d_in[6];
  const float* bih  = (const float*)d_in[7];
  const float* bhh  = (const float*)d_in[8];
  const float* fcW  = (const float*)d_in[9];
  const float* fcb  = (const float*)d_in[10];
  const float* fc2W = (const float*)d_in[11];
  const float* fc2b = (const float*)d_in[12];
  const float* fc3W = (const float*)d_in[13];
  const float* fc3b = (const float*)d_in[14];

  unsigned* bar = (unsigned*)d_ws;
  float* wsf = (float*)((char*)d_ws + 1024);
  float* wsT = wsf + 10*SZ;   // 16MB weight block area

  (void)hipMemsetAsync(d_ws, 0, 1024, stream);

  hipLaunchKernelGGL(transpose_weights, dim3(NWG), dim3(256), 0, stream,
                     Wih, Whh, wsT);
  hipLaunchKernelGGL(decoder_kernel, dim3(NWG), dim3(NTHR), 0, stream,
                     h0, c0, cnd, emb, wsT, bih, bhh, fcW, fcb,
                     fc2W, fc2b, fc3W, fc3b, (float*)d_out, bar, wsf);
}